// Round 5
// baseline (49.709 us; speedup 1.0000x reference)
//
#include <hip/hip_runtime.h>
#include <stdint.h>

typedef unsigned short u16;
typedef __attribute__((ext_vector_type(4))) u16    u16x4;
typedef __attribute__((ext_vector_type(8))) u16    u16x8;
typedef __attribute__((ext_vector_type(4))) float  f32x4;
typedef __attribute__((ext_vector_type(8))) __bf16 bf16x8;

__device__ __forceinline__ u16 f2bf(float f) {
    union { float f; uint32_t u; } v; v.f = f;
    uint32_t u = v.u;
    uint32_t rb = 0x7FFFu + ((u >> 16) & 1u);
    return (u16)((u + rb) >> 16);
}

// ---------------- kernel 0: W[k][f] -> Wt[f][k] bf16 ----------------
__global__ __launch_bounds__(256) void gcn_wt(const float* __restrict__ W,
                                              u16* __restrict__ Wt) {
    int idx = blockIdx.x * 256 + threadIdx.x;   // 0..16383
    int k = idx >> 7, f = idx & 127;
    Wt[f * 128 + k] = f2bf(W[idx]);
}

// ---------------- fused: out = relu((adj@x)@W + rowsum(adj)*b + x) ------
// Per block: 64 adj rows. Phase 1: y = adj_blk @ x (K=1024, 16 tiles of 64
// nodes; x transposed to [f][n] in LDS during staging). Phase 2: z = y @ W
// (K=128; A-frags from LDS Yl, B-frags from global Wt, L2-hot).
// 512 threads = 8 waves (4 row-groups x 2 col-halves), wave tile 16x64.
__global__ __launch_bounds__(512, 4) void gcn_fused(const float* __restrict__ adj,
                                                    const float* __restrict__ x,
                                                    const u16* __restrict__ Wt,
                                                    const float* __restrict__ bias,
                                                    float* __restrict__ out) {
    __shared__ u16   Al[2][64 * 64];     // adj tile [r][n] bf16, swizzled, 8 KB ea
    __shared__ u16   Xt[2][128 * 72];    // x^T tile [f][n] bf16, pitch 144 B, 18 KB ea
    __shared__ u16   Yl[64 * 128];       // y [r][m] bf16, 256B rows swizzled, 16 KB
    __shared__ float Rs[64];             // rowsum(adj) per local row

    const int t = threadIdx.x;           // 0..511
    // bijective XCD swizzle: 512 blocks, 64 per XCD; one XCD owns 4 batches
    const int L  = (blockIdx.x & 7) * 64 + (blockIdx.x >> 3);
    const int bb = L >> 4;
    const int r0 = (L & 15) << 6;

    const float* adjb = adj + (size_t)bb * 1048576 + (size_t)r0 * 1024;
    const float* xb   = x + (size_t)bb * 131072;

    const int w = t >> 6, l = t & 63;
    const int wr = w >> 1, wc = w & 1;   // 4x2 wave grid: 16 rows x 64 cols

    // adj staging: row rA=t>>3, 8 floats at n-offset k8*8
    const int rA = t >> 3, k8 = t & 7;
    const float* gA = adjb + (size_t)rA * 1024 + k8 * 8;
    const int ldsA = rA * 128 + ((k8 * 16) ^ ((rA & 7) << 4));

    // x staging: 16 scalar floats/thread/tile. elem e = i*512+t:
    //   n = i*4 + wr, f = wc*64 + l  -> addr = xb + (nt+n)*128 + f
    const float* gX = xb + (size_t)wr * 128 + wc * 64 + l;
    // LDS dest: Xt[f][n] byte = f*144 + 2n = (wc*64+l)*144 + 2*wr + i*8
    const int xWb = (wc * 64 + l) * 144 + 2 * wr;

    float rsum = 0.0f;

#define LOADT(ar, xr, ks)                                       \
    do {                                                        \
        const int n0_ = (ks) * 64;                              \
        ar[0] = *(const f32x4*)(gA + n0_);                      \
        ar[1] = *(const f32x4*)(gA + n0_ + 4);                  \
        _Pragma("unroll")                                       \
        for (int i = 0; i < 16; ++i)                            \
            xr[i] = gX[(size_t)n0_ * 128 + i * 512];            \
    } while (0)

#define WRITET(buf, ar, xr)                                     \
    do {                                                        \
        u16x8 ha;                                               \
        ha[0] = f2bf(ar[0].x); ha[1] = f2bf(ar[0].y);           \
        ha[2] = f2bf(ar[0].z); ha[3] = f2bf(ar[0].w);           \
        ha[4] = f2bf(ar[1].x); ha[5] = f2bf(ar[1].y);           \
        ha[6] = f2bf(ar[1].z); ha[7] = f2bf(ar[1].w);           \
        *(u16x8*)((char*)&Al[buf][0] + ldsA) = ha;              \
        rsum += ar[0].x + ar[0].y + ar[0].z + ar[0].w           \
              + ar[1].x + ar[1].y + ar[1].z + ar[1].w;          \
        _Pragma("unroll")                                       \
        for (int i = 0; i < 16; ++i)                            \
            *(u16*)((char*)&Xt[buf][0] + xWb + i * 8) = f2bf(xr[i]); \
    } while (0)

#define BARRIER() asm volatile("s_waitcnt lgkmcnt(0)\ns_barrier" ::: "memory")

#define COMPUTE(buf)                                                            \
    do {                                                                        \
        _Pragma("unroll")                                                       \
        for (int kk = 0; kk < 2; ++kk) {                                        \
            const int kbyteA = kk * 64 + (l >> 4) * 16;                         \
            const int rl = wr * 16 + (l & 15);                                  \
            bf16x8 a = *(const bf16x8*)((const char*)&Al[buf][0] + rl * 128 +   \
                                        (kbyteA ^ ((rl & 7) << 4)));            \
            bf16x8 b[4];                                                        \
            _Pragma("unroll")                                                   \
            for (int nn = 0; nn < 4; ++nn) {                                    \
                int fm = wc * 64 + nn * 16 + (l & 15);                          \
                b[nn] = *(const bf16x8*)((const char*)&Xt[buf][0] + fm * 144 +  \
                                         kk * 64 + (l >> 4) * 16);              \
            }                                                                   \
            _Pragma("unroll")                                                   \
            for (int nn = 0; nn < 4; ++nn)                                      \
                acc[nn] = __builtin_amdgcn_mfma_f32_16x16x32_bf16(              \
                    a, b[nn], acc[nn], 0, 0, 0);                                \
        }                                                                       \
    } while (0)

    f32x4 acc[4] = {};
    f32x4 a0[2], a1[2];
    float xs0[16], xs1[16];

    LOADT(a0, xs0, 0);
    LOADT(a1, xs1, 1);
#pragma unroll
    for (int ks = 0; ks < 16; ks += 2) {
        WRITET(0, a0, xs0);
        BARRIER();
        if (ks + 2 < 16) LOADT(a0, xs0, ks + 2);
        COMPUTE(0);
        WRITET(1, a1, xs1);
        BARRIER();
        if (ks + 3 < 16) LOADT(a1, xs1, ks + 3);
        COMPUTE(1);
    }
#undef LOADT
#undef WRITET
#undef BARRIER
#undef COMPUTE

    // rowsum: 8 threads (consecutive lanes) share row rA
    rsum += __shfl_xor(rsum, 1);
    rsum += __shfl_xor(rsum, 2);
    rsum += __shfl_xor(rsum, 4);
    if ((t & 7) == 0) Rs[rA] = rsum;

    // y -> Yl (bf16, [r][m], 256B rows, 16B-granule XOR swizzle)
#pragma unroll
    for (int nn = 0; nn < 4; ++nn)
#pragma unroll
        for (int j = 0; j < 4; ++j) {
            int r = wr * 16 + (l >> 4) * 4 + j;
            int c = wc * 64 + nn * 16 + (l & 15);
            *(u16*)((char*)Yl + r * 256 + ((c * 2) ^ ((r & 7) << 4))) =
                f2bf(acc[nn][j]);
        }
    __syncthreads();

    // phase 2: z = y @ W  (K=128; B-frags from global Wt[f][k], L2-hot)
    f32x4 z[4] = {};
    const int rl2 = wr * 16 + (l & 15);
#pragma unroll
    for (int kk = 0; kk < 4; ++kk) {
        const int kbyte = kk * 64 + (l >> 4) * 16;
        bf16x8 a = *(const bf16x8*)((const char*)Yl + rl2 * 256 +
                                    (kbyte ^ ((rl2 & 7) << 4)));
#pragma unroll
        for (int nn = 0; nn < 4; ++nn) {
            int f = wc * 64 + nn * 16 + (l & 15);
            int k = kk * 32 + (l >> 4) * 8;
            bf16x8 b = *(const bf16x8*)(Wt + (size_t)f * 128 + k);
            z[nn] = __builtin_amdgcn_mfma_f32_16x16x32_bf16(a, b, z[nn], 0, 0, 0);
        }
    }

    // epilogue: + rowsum*b + x, relu, fp32 store
    float* ob = out + (size_t)bb * 131072;
#pragma unroll
    for (int nn = 0; nn < 4; ++nn) {
        int f = wc * 64 + nn * 16 + (l & 15);
        float bv = bias[f];
#pragma unroll
        for (int j = 0; j < 4; ++j) {
            int r = wr * 16 + (l >> 4) * 4 + j;
            size_t idx = (size_t)(r0 + r) * 128 + f;
            float v = z[nn][j] + Rs[r] * bv + xb[idx];
            ob[idx] = fmaxf(v, 0.0f);
        }
    }
}

extern "C" void kernel_launch(void* const* d_in, const int* in_sizes, int n_in,
                              void* d_out, int out_size, void* d_ws, size_t ws_size,
                              hipStream_t stream) {
    const float* x    = (const float*)d_in[0];
    const float* adj  = (const float*)d_in[1];
    const float* W    = (const float*)d_in[2];
    const float* bias = (const float*)d_in[3];
    float* out = (float*)d_out;

    u16* Wt = (u16*)d_ws;   // 32 KiB

    gcn_wt   <<<dim3(64),  dim3(256), 0, stream>>>(W, Wt);
    gcn_fused<<<dim3(512), dim3(512), 0, stream>>>(adj, x, Wt, bias, out);
}

// Round 6
// 42.316 us; speedup vs baseline: 1.1747x; 1.1747x over previous
//
#include <hip/hip_runtime.h>
#include <stdint.h>

typedef unsigned short u16;
typedef __attribute__((ext_vector_type(4))) u16    u16x4;
typedef __attribute__((ext_vector_type(8))) u16    u16x8;
typedef __attribute__((ext_vector_type(4))) float  f32x4;
typedef __attribute__((ext_vector_type(8))) __bf16 bf16x8;

union BF8 { u16x8 u; bf16x8 b; };
union BF4x2 { struct { u16x4 lo, hi; } p; bf16x8 b; };

__device__ __forceinline__ u16 f2bf(float f) {
    union { float f; uint32_t u; } v; v.f = f;
    uint32_t u = v.u;
    uint32_t rb = 0x7FFFu + ((u >> 16) & 1u);
    return (u16)((u + rb) >> 16);
}

// ONE kernel: out = relu(adj @ (x@W + b) + x)
// Per block: 64 adj rows of one batch. Per K-tile (64 nodes):
//   h_tile = x_tile @ W + b   via MFMA, k=feature-in contiguous (x row-major!)
//   y     += adj_tile @ h_tile  with h's D-regs fed DIRECTLY as B-frags
//            (slot-permutation pi(g,j) = {g*4+j, 16+g*4+(j-4)}; adj A-frags
//             loaded with the matching pi via two ds_read_b64)
// Wave w owns f-block w (16 features). W-frags register-resident.
// Residual x stashed from the in-flight x-tile when ks == own row-block.
__global__ __launch_bounds__(512, 4) void gcn_one(const float* __restrict__ adj,
                                                  const float* __restrict__ x,
                                                  const float* __restrict__ W,
                                                  const float* __restrict__ bias,
                                                  float* __restrict__ out) {
    __shared__ u16 Al[2][64 * 64];    // adj tile bf16 [r][n], 128B rows, XOR bits[6:3]
    __shared__ u16 Xl[2][64 * 128];   // x   tile bf16 [n][g], 256B rows, XOR bits[6:4]
    __shared__ u16 Xr[64 * 128];      // residual copy of own x rows

    const int t = threadIdx.x;        // 0..511
    // bijective XCD swizzle: 64 blocks/XCD; one XCD owns 4 whole batches
    const int L = (blockIdx.x & 7) * 64 + (blockIdx.x >> 3);
    const int bb = L >> 4;
    const int myblk = L & 15;
    const int r0 = myblk << 6;

    const float* adjb = adj + (size_t)bb * 1048576 + (size_t)r0 * 1024;
    const float* xb   = x + (size_t)bb * 131072;

    const int w = t >> 6, l = t & 63;
    const int lg = l >> 4, lc = l & 15;
    const int f = w * 16 + lc;        // this wave's feature column for this lane

    // ---- one-time: bias + W B-frags (k = g contiguous), register-resident ----
    const float bv = bias[f];
    BF8 wf[4];
#pragma unroll
    for (int gs = 0; gs < 4; ++gs)
#pragma unroll
        for (int j = 0; j < 8; ++j)
            wf[gs].b[j] = (__bf16)W[(size_t)(gs * 32 + lg * 8 + j) * 128 + f];

    // ---- staging geometry ----
    const int rA0 = t >> 4;                 // adj rows (second chunk: +32)
    const int rA1 = rA0 + 32;
    const int aOff = (t & 15) * 8;          // byte within 128B adj row
    const int ldsA0 = rA0 * 128 + (aOff ^ (((rA0 & 7) << 4) | (rA0 & 8)));
    const int ldsA1 = rA1 * 128 + (aOff ^ (((rA1 & 7) << 4) | (rA1 & 8)));
    const float* gA0 = adjb + (size_t)rA0 * 1024 + (t & 15) * 4;
    const float* gA1 = adjb + (size_t)rA1 * 1024 + (t & 15) * 4;

    const int xOff = (t & 31) * 8;          // byte within 256B x row
    int ldsX[4];
    const float* gX[4];
#pragma unroll
    for (int i = 0; i < 4; ++i) {
        int n = (t >> 5) + i * 16;
        ldsX[i] = n * 256 + (xOff ^ ((n & 7) << 4));
        gX[i] = xb + (size_t)n * 128 + (t & 31) * 4;
    }

#define LOADT(ar, xr, ks)                                         \
    do {                                                          \
        ar[0] = *(const f32x4*)(gA0 + (ks) * 64);                 \
        ar[1] = *(const f32x4*)(gA1 + (ks) * 64);                 \
        _Pragma("unroll")                                         \
        for (int i = 0; i < 4; ++i)                               \
            xr[i] = *(const f32x4*)(gX[i] + (size_t)(ks) * 8192); \
    } while (0)

#define WRITET(buf, ar, xr)                                              \
    do {                                                                 \
        u16x4 h0, h1;                                                    \
        h0.x = f2bf(ar[0].x); h0.y = f2bf(ar[0].y);                      \
        h0.z = f2bf(ar[0].z); h0.w = f2bf(ar[0].w);                      \
        h1.x = f2bf(ar[1].x); h1.y = f2bf(ar[1].y);                      \
        h1.z = f2bf(ar[1].z); h1.w = f2bf(ar[1].w);                      \
        *(u16x4*)((char*)&Al[buf][0] + ldsA0) = h0;                      \
        *(u16x4*)((char*)&Al[buf][0] + ldsA1) = h1;                      \
        _Pragma("unroll")                                                \
        for (int i = 0; i < 4; ++i) {                                    \
            u16x4 hx;                                                    \
            hx.x = f2bf(xr[i].x); hx.y = f2bf(xr[i].y);                  \
            hx.z = f2bf(xr[i].z); hx.w = f2bf(xr[i].w);                  \
            *(u16x4*)((char*)&Xl[buf][0] + ldsX[i]) = hx;                \
        }                                                                \
    } while (0)

// lgkmcnt drain + barrier; vmcnt (global prefetch) stays in flight.
#define BARRIER() asm volatile("s_waitcnt lgkmcnt(0)\ns_barrier" ::: "memory")

#define COPYRESID(buf)                                                        \
    do {                                                                      \
        u16x8 c0 = *(const u16x8*)((const char*)&Xl[buf][0] + t * 32);        \
        u16x8 c1 = *(const u16x8*)((const char*)&Xl[buf][0] + t * 32 + 16);   \
        *(u16x8*)((char*)Xr + t * 32)      = c0;                              \
        *(u16x8*)((char*)Xr + t * 32 + 16) = c1;                              \
    } while (0)

#define COMPUTE(buf)                                                               \
    do {                                                                           \
        f32x4 hacc[4];                                                             \
        _Pragma("unroll")                                                          \
        for (int nb = 0; nb < 4; ++nb) {                                           \
            f32x4 hv = {bv, bv, bv, bv};                                           \
            hacc[nb] = hv;                                                         \
        }                                                                          \
        _Pragma("unroll")                                                          \
        for (int gs = 0; gs < 4; ++gs) {                                           \
            _Pragma("unroll")                                                      \
            for (int nb = 0; nb < 4; ++nb) {                                       \
                int n = nb * 16 + lc;                                              \
                BF8 xa;                                                            \
                xa.u = *(const u16x8*)((const char*)&Xl[buf][0] + n * 256 +        \
                                       ((gs * 64 + lg * 16) ^ ((n & 7) << 4)));    \
                hacc[nb] = __builtin_amdgcn_mfma_f32_16x16x32_bf16(                \
                    xa.b, wf[gs].b, hacc[nb], 0, 0, 0);                            \
            }                                                                      \
        }                                                                          \
        BF8 hb0, hb1;                                                              \
        hb0.b[0] = (__bf16)hacc[0].x; hb0.b[1] = (__bf16)hacc[0].y;                \
        hb0.b[2] = (__bf16)hacc[0].z; hb0.b[3] = (__bf16)hacc[0].w;                \
        hb0.b[4] = (__bf16)hacc[1].x; hb0.b[5] = (__bf16)hacc[1].y;                \
        hb0.b[6] = (__bf16)hacc[1].z; hb0.b[7] = (__bf16)hacc[1].w;                \
        hb1.b[0] = (__bf16)hacc[2].x; hb1.b[1] = (__bf16)hacc[2].y;                \
        hb1.b[2] = (__bf16)hacc[2].z; hb1.b[3] = (__bf16)hacc[2].w;                \
        hb1.b[4] = (__bf16)hacc[3].x; hb1.b[5] = (__bf16)hacc[3].y;                \
        hb1.b[6] = (__bf16)hacc[3].z; hb1.b[7] = (__bf16)hacc[3].w;                \
        _Pragma("unroll")                                                          \
        for (int kn = 0; kn < 2; ++kn) {                                           \
            _Pragma("unroll")                                                      \
            for (int rb = 0; rb < 4; ++rb) {                                       \
                int r = rb * 16 + lc;                                              \
                int msk = ((r & 7) << 4) | (r & 8);                                \
                BF4x2 af;                                                          \
                af.p.lo = *(const u16x4*)((const char*)&Al[buf][0] + r * 128 +     \
                                          ((kn * 64 + lg * 8) ^ msk));             \
                af.p.hi = *(const u16x4*)((const char*)&Al[buf][0] + r * 128 +     \
                                          ((kn * 64 + 32 + lg * 8) ^ msk));        \
                yacc[rb] = __builtin_amdgcn_mfma_f32_16x16x32_bf16(                \
                    af.b, (kn ? hb1.b : hb0.b), yacc[rb], 0, 0, 0);                \
            }                                                                      \
        }                                                                          \
    } while (0)

    f32x4 yacc[4] = {};
    f32x4 ar[2];
    f32x4 xr[4];

    LOADT(ar, xr, 0);
#pragma unroll
    for (int ks = 0; ks < 16; ++ks) {
        const int buf = ks & 1;
        WRITET(buf, ar, xr);
        BARRIER();
        if (ks + 1 < 16) LOADT(ar, xr, ks + 1);   // prefetch flies over MFMA
        if (ks == myblk) COPYRESID(buf);
        COMPUTE(buf);
    }
#undef LOADT
#undef WRITET
#undef BARRIER
#undef COPYRESID
#undef COMPUTE

    __syncthreads();   // Xr fully visible

    // epilogue: + x (bf16 residual from LDS), relu, fp32 store
    float* ob = out + (size_t)bb * 131072 + (size_t)r0 * 128;
#pragma unroll
    for (int rb = 0; rb < 4; ++rb)
#pragma unroll
        for (int j = 0; j < 4; ++j) {
            int rr = rb * 16 + lg * 4 + j;
            u16 xv = *(const u16*)((const char*)Xr + rr * 256 +
                                   ((f * 2) ^ ((rr & 7) << 4)));
            union { float ff; uint32_t uu; } cv;
            cv.uu = (uint32_t)xv << 16;
            float v = yacc[rb][j] + cv.ff;
            ob[(size_t)rr * 128 + f] = fmaxf(v, 0.0f);
        }
}

extern "C" void kernel_launch(void* const* d_in, const int* in_sizes, int n_in,
                              void* d_out, int out_size, void* d_ws, size_t ws_size,
                              hipStream_t stream) {
    const float* x    = (const float*)d_in[0];
    const float* adj  = (const float*)d_in[1];
    const float* W    = (const float*)d_in[2];
    const float* bias = (const float*)d_in[3];
    float* out = (float*)d_out;

    gcn_one<<<dim3(512), dim3(512), 0, stream>>>(adj, x, W, bias, out);
}